// Round 2
// baseline (1588.244 us; speedup 1.0000x reference)
//
#include <hip/hip_runtime.h>
#include <float.h>

// Sparsemax attention, MFMA edition.
// B=2,H=16,S=2048,D=64 fp32, temperature 8.
// Block = 32 q-rows (512 thr, 8 waves). Wave w computes scores for cols
// [w*256,(w+1)*256) x 32 rows via mfma_f32_16x16x32_bf16, scores stay in
// VGPRs (acc[2][16] f32x4). Row-max via frag + shfl + LDS; candidates
// {raw > rawmax-8.5} -> LDS lists; exact fp32 recompute of candidates;
// Michelot tau; sparse PV. Dense VALU fallback per row on CAP overflow.

#define S_LEN 2048
#define DHEAD 64
#define BROWS 32
#define NWAVES 8
#define CAP 64
#define NCT 16

typedef __attribute__((ext_vector_type(8))) short bf16x8;
typedef __attribute__((ext_vector_type(4))) float f32x4;

__device__ __forceinline__ unsigned int f2bf(float x) {
    unsigned int u = __builtin_bit_cast(unsigned int, x);
    return (u + 0x7FFFu + ((u >> 16) & 1u)) >> 16;   // RNE
}
__device__ __forceinline__ unsigned int pk2(float lo, float hi) {
    return f2bf(lo) | (f2bf(hi) << 16);
}
__device__ __forceinline__ bf16x8 cvt8(float4 a, float4 b) {
    union { unsigned int u[4]; bf16x8 v; } r;
    r.u[0] = pk2(a.x, a.y); r.u[1] = pk2(a.z, a.w);
    r.u[2] = pk2(b.x, b.y); r.u[3] = pk2(b.z, b.w);
    return r.v;
}

__global__ __launch_bounds__(256)
void cvt_bf16_kernel(const float* __restrict__ src, uint4* __restrict__ dst, int n8) {
    int i = blockIdx.x * 256 + threadIdx.x;
    if (i >= n8) return;
    const float4* s4 = reinterpret_cast<const float4*>(src);
    float4 a = s4[2 * i], b = s4[2 * i + 1];
    uint4 o;
    o.x = pk2(a.x, a.y); o.y = pk2(a.z, a.w);
    o.z = pk2(b.x, b.y); o.w = pk2(b.z, b.w);
    dst[i] = o;
}

template<bool PRE>
__global__ __launch_bounds__(512, 2)
void spx_main(const float* __restrict__ Q, const float* __restrict__ K,
              const float* __restrict__ V, float* __restrict__ O,
              const unsigned short* __restrict__ Qb,
              const unsigned short* __restrict__ Kb)
{
    __shared__ float s_wmax[NWAVES][BROWS];
    __shared__ float s_rmax[BROWS];
    __shared__ int   s_cnt[BROWS];
    __shared__ int   s_ccol[BROWS][CAP];
    __shared__ float s_fb[NWAVES][S_LEN];     // fallback scratch (64 KB)

    const int t  = threadIdx.x;
    const int w  = t >> 6;
    const int l  = t & 63;
    const int lm = l & 15;       // M/N index in MFMA tile
    const int lk = l >> 4;       // k-group

    int bid = blockIdx.x;
    if (((int)gridDim.x & 7) == 0)
        bid = (bid & 7) * ((int)gridDim.x >> 3) + (bid >> 3);   // XCD swizzle
    const int nrb  = S_LEN / BROWS;
    const int bh   = bid / nrb;
    const int rb   = bid % nrb;
    const int row0 = rb * BROWS;

    const size_t bhoff = (size_t)bh * S_LEN * DHEAD;
    const float* Qf = Q + bhoff;
    const float* Kf = K + bhoff;
    const float* Vf = V + bhoff;
    float*       Of = O + bhoff;

    if (t < BROWS) s_cnt[t] = 0;

    // ---- A fragments: Q[row0+rt*16+lm][kp*32 + lk*8 + 0..7] ----
    bf16x8 afrag[2][2];
    #pragma unroll
    for (int rt = 0; rt < 2; ++rt)
        #pragma unroll
        for (int kp = 0; kp < 2; ++kp) {
            const int r  = row0 + rt * 16 + lm;
            const int d0 = kp * 32 + lk * 8;
            if (PRE) {
                afrag[rt][kp] = *reinterpret_cast<const bf16x8*>(
                    Qb + bhoff + (size_t)r * DHEAD + d0);
            } else {
                float4 a = *reinterpret_cast<const float4*>(Qf + (size_t)r * DHEAD + d0);
                float4 b = *reinterpret_cast<const float4*>(Qf + (size_t)r * DHEAD + d0 + 4);
                afrag[rt][kp] = cvt8(a, b);
            }
        }

    // ---- phase 1: MFMA, scores stay in VGPRs ----
    const int col0 = w * 256;
    f32x4 acc[2][NCT];
    #pragma unroll
    for (int rt = 0; rt < 2; ++rt)
        #pragma unroll
        for (int ct = 0; ct < NCT; ++ct)
            acc[rt][ct] = (f32x4){0.f, 0.f, 0.f, 0.f};

    #pragma unroll 4
    for (int ct = 0; ct < NCT; ++ct) {
        const int kc = col0 + ct * 16 + lm;
        bf16x8 b0, b1;
        if (PRE) {
            const unsigned short* kp8 = Kb + bhoff + (size_t)kc * DHEAD;
            b0 = *reinterpret_cast<const bf16x8*>(kp8 + lk * 8);
            b1 = *reinterpret_cast<const bf16x8*>(kp8 + 32 + lk * 8);
        } else {
            const float* kp = Kf + (size_t)kc * DHEAD;
            float4 a0 = *reinterpret_cast<const float4*>(kp + lk * 8);
            float4 a1 = *reinterpret_cast<const float4*>(kp + lk * 8 + 4);
            float4 c0 = *reinterpret_cast<const float4*>(kp + 32 + lk * 8);
            float4 c1 = *reinterpret_cast<const float4*>(kp + 32 + lk * 8 + 4);
            b0 = cvt8(a0, a1);
            b1 = cvt8(c0, c1);
        }
        acc[0][ct] = __builtin_amdgcn_mfma_f32_16x16x32_bf16(afrag[0][0], b0, acc[0][ct], 0, 0, 0);
        acc[0][ct] = __builtin_amdgcn_mfma_f32_16x16x32_bf16(afrag[0][1], b1, acc[0][ct], 0, 0, 0);
        acc[1][ct] = __builtin_amdgcn_mfma_f32_16x16x32_bf16(afrag[1][0], b0, acc[1][ct], 0, 0, 0);
        acc[1][ct] = __builtin_amdgcn_mfma_f32_16x16x32_bf16(afrag[1][1], b1, acc[1][ct], 0, 0, 0);
    }

    // ---- row max: per-lane over frags, then across the 16 lm lanes ----
    float pm[2][4];
    #pragma unroll
    for (int rt = 0; rt < 2; ++rt)
        #pragma unroll
        for (int e = 0; e < 4; ++e) {
            float m = acc[rt][0][e];
            #pragma unroll
            for (int ct = 1; ct < NCT; ++ct) m = fmaxf(m, acc[rt][ct][e]);
            pm[rt][e] = m;
        }
    #pragma unroll
    for (int o = 1; o < 16; o <<= 1)
        #pragma unroll
        for (int rt = 0; rt < 2; ++rt)
            #pragma unroll
            for (int e = 0; e < 4; ++e)
                pm[rt][e] = fmaxf(pm[rt][e], __shfl_xor(pm[rt][e], o));
    if (lm == 0) {
        #pragma unroll
        for (int rt = 0; rt < 2; ++rt)
            #pragma unroll
            for (int e = 0; e < 4; ++e)
                s_wmax[w][rt * 16 + lk * 4 + e] = pm[rt][e];
    }
    __syncthreads();
    if (t < BROWS) {
        float m = s_wmax[0][t];
        #pragma unroll
        for (int ww = 1; ww < NWAVES; ++ww) m = fmaxf(m, s_wmax[ww][t]);
        s_rmax[t] = m;
    }
    __syncthreads();

    // ---- candidate collect (raw units: s/8 > max/8 - 1 - margin) ----
    float thr[2][4];
    #pragma unroll
    for (int rt = 0; rt < 2; ++rt)
        #pragma unroll
        for (int e = 0; e < 4; ++e)
            thr[rt][e] = s_rmax[rt * 16 + lk * 4 + e] - 8.5f;

    #pragma unroll
    for (int rt = 0; rt < 2; ++rt)
        #pragma unroll
        for (int ct = 0; ct < NCT; ++ct)
            #pragma unroll
            for (int e = 0; e < 4; ++e) {
                float v = acc[rt][ct][e];
                if (v > thr[rt][e]) {
                    int row = rt * 16 + lk * 4 + e;
                    int pos = atomicAdd(&s_cnt[row], 1);
                    if (pos < CAP) s_ccol[row][pos] = col0 + ct * 16 + lm;
                }
            }
    __syncthreads();

    // ---- phase 2: wave w owns block-rows w*4..w*4+3 ----
    float qv[4];
    int   n[4];
    bool  ovf[4];
    #pragma unroll
    for (int j = 0; j < 4; ++j) {
        int r = w * 4 + j;
        qv[j] = Qf[(size_t)(row0 + r) * DHEAD + l];
        int c = s_cnt[r];
        ovf[j] = (c > CAP);
        n[j] = ovf[j] ? 0 : c;
    }
    int nmax = n[0];
    #pragma unroll
    for (int j = 1; j < 4; ++j) nmax = n[j] > nmax ? n[j] : nmax;

    // exact fp32 recompute of candidate scores (lane i holds candidate i)
    float sval[4] = {0.f, 0.f, 0.f, 0.f};
    for (int i = 0; i < nmax; ++i) {
        float d[4];
        #pragma unroll
        for (int j = 0; j < 4; ++j) {
            int cc = (i < n[j]) ? s_ccol[w * 4 + j][i] : 0;
            d[j] = qv[j] * Kf[(size_t)cc * DHEAD + l];
        }
        #pragma unroll
        for (int o = 1; o < 64; o <<= 1)
            #pragma unroll
            for (int j = 0; j < 4; ++j) d[j] += __shfl_xor(d[j], o);
        #pragma unroll
        for (int j = 0; j < 4; ++j)
            if (l == i) sval[j] = d[j] * 0.125f;
    }

    // Michelot: exact tau in finitely many steps (support subset of candidates)
    float tau[4];
    #pragma unroll
    for (int j = 0; j < 4; ++j) {
        float tj = 0.f;
        if (n[j] > 0) {
            float v = (l < n[j]) ? sval[j] : -FLT_MAX;
            tj = -3.0e38f;
            int last = -1;
            for (int it = 0; it < CAP + 2; ++it) {
                float sm = (v > tj) ? v : 0.f;
                int   c  = (v > tj) ? 1 : 0;
                #pragma unroll
                for (int o = 1; o < 64; o <<= 1) {
                    sm += __shfl_xor(sm, o);
                    c  += __shfl_xor(c, o);
                }
                if (c == last) break;
                tj = (sm - 1.f) / (float)c;
                last = c;
            }
        }
        tau[j] = tj;
    }

    // sparse PV
    float oacc[4] = {0.f, 0.f, 0.f, 0.f};
    for (int i = 0; i < nmax; ++i) {
        #pragma unroll
        for (int j = 0; j < 4; ++j) {
            if (i < n[j]) {
                float p = __shfl(sval[j], i) - tau[j];
                if (p > 0.f) {
                    int c = s_ccol[w * 4 + j][i];
                    oacc[j] += p * Vf[(size_t)c * DHEAD + l];
                }
            }
        }
    }
    #pragma unroll
    for (int j = 0; j < 4; ++j)
        if (!ovf[j])
            Of[(size_t)(row0 + w * 4 + j) * DHEAD + l] = oacc[j];

    // ---- fallback: dense recompute per overflowed row (never hit for
    //      Gaussian inputs; kept for correctness on any data) ----
    #pragma unroll
    for (int j = 0; j < 4; ++j) {
        if (ovf[j]) {
            const int qrow = row0 + w * 4 + j;
            const float* qp = Qf + (size_t)qrow * DHEAD;
            for (int c0 = 0; c0 < S_LEN; c0 += 64) {
                int c = c0 + l;
                const float* kp = Kf + (size_t)c * DHEAD;
                float s = 0.f;
                for (int dd = 0; dd < DHEAD; ++dd) s = fmaf(qp[dd], kp[dd], s);
                s_fb[w][c] = s * 0.125f;
            }
            float m = -FLT_MAX;
            for (int c0 = 0; c0 < S_LEN; c0 += 64) m = fmaxf(m, s_fb[w][c0 + l]);
            #pragma unroll
            for (int o = 1; o < 64; o <<= 1) m = fmaxf(m, __shfl_xor(m, o));
            float lo = m - 1.f, hi = m;
            for (int it = 0; it < 50; ++it) {
                float mid = 0.5f * (lo + hi);
                float sm = 0.f;
                for (int c0 = 0; c0 < S_LEN; c0 += 64)
                    sm += fmaxf(s_fb[w][c0 + l] - mid, 0.f);
                #pragma unroll
                for (int o = 1; o < 64; o <<= 1) sm += __shfl_xor(sm, o);
                if (sm > 1.f) lo = mid; else hi = mid;
            }
            float sm = 0.f; int c = 0;
            for (int c0 = 0; c0 < S_LEN; c0 += 64) {
                float s = s_fb[w][c0 + l];
                if (s > lo) { sm += s; ++c; }
            }
            #pragma unroll
            for (int o = 1; o < 64; o <<= 1) { sm += __shfl_xor(sm, o); c += __shfl_xor(c, o); }
            float tj = (sm - 1.f) / (float)c;
            float oa = 0.f;
            for (int k = 0; k < S_LEN; ++k) {
                float p = s_fb[w][k] - tj;
                if (p > 0.f) oa += p * Vf[(size_t)k * DHEAD + l];
            }
            Of[(size_t)qrow * DHEAD + l] = oa;
        }
    }
}

extern "C" void kernel_launch(void* const* d_in, const int* in_sizes, int n_in,
                              void* d_out, int out_size, void* d_ws, size_t ws_size,
                              hipStream_t stream) {
    const float* q = (const float*)d_in[0];
    const float* k = (const float*)d_in[1];
    const float* v = (const float*)d_in[2];
    float* out = (float*)d_out;

    const int nElem = in_sizes[0];                     // B*H*S*D
    const int BH    = nElem / (S_LEN * DHEAD);
    const int grid  = BH * (S_LEN / BROWS);

    const size_t need = (size_t)nElem * 2u * sizeof(unsigned short);
    if (ws_size >= need) {
        unsigned short* qb = (unsigned short*)d_ws;
        unsigned short* kb = qb + nElem;
        int n8 = nElem / 8;
        cvt_bf16_kernel<<<(n8 + 255) / 256, 256, 0, stream>>>(q, (uint4*)qb, n8);
        cvt_bf16_kernel<<<(n8 + 255) / 256, 256, 0, stream>>>(k, (uint4*)kb, n8);
        spx_main<true><<<grid, 512, 0, stream>>>(q, k, v, out, qb, kb);
    } else {
        spx_main<false><<<grid, 512, 0, stream>>>(q, k, v, out, nullptr, nullptr);
    }
}